// Round 11
// baseline (186.732 us; speedup 1.0000x reference)
//
#include <hip/hip_runtime.h>
#include <stdint.h>

#define S_LEN 2048
#define DMODEL 1024
#define NBATCH 4
#define MROWS (NBATCH * S_LEN)  // 8192

typedef __bf16 bf16x8 __attribute__((ext_vector_type(8)));
typedef float f32x4 __attribute__((ext_vector_type(4)));
typedef float f32x16 __attribute__((ext_vector_type(16)));

__device__ __forceinline__ unsigned short f2bf(float f) {
  unsigned int x = __builtin_bit_cast(unsigned int, f);
  x += 0x7FFFu + ((x >> 16) & 1u);
  return (unsigned short)(x >> 16);
}

template <int N>
__device__ __forceinline__ void waitvm() {
  static_assert(N <= 8, "vmcnt range");
  if constexpr (N < 0) {}
  else if constexpr (N == 0) asm volatile("s_waitcnt vmcnt(0)" ::: "memory");
  else if constexpr (N == 1) asm volatile("s_waitcnt vmcnt(1)" ::: "memory");
  else if constexpr (N == 2) asm volatile("s_waitcnt vmcnt(2)" ::: "memory");
  else if constexpr (N == 3) asm volatile("s_waitcnt vmcnt(3)" ::: "memory");
  else if constexpr (N == 4) asm volatile("s_waitcnt vmcnt(4)" ::: "memory");
  else if constexpr (N == 5) asm volatile("s_waitcnt vmcnt(5)" ::: "memory");
  else if constexpr (N == 6) asm volatile("s_waitcnt vmcnt(6)" ::: "memory");
  else if constexpr (N == 7) asm volatile("s_waitcnt vmcnt(7)" ::: "memory");
  else asm volatile("s_waitcnt vmcnt(8)" ::: "memory");
}
#define BARRIER() do { __builtin_amdgcn_s_barrier(); asm volatile("" ::: "memory"); } while (0)

// ---------------- convert f32 -> bf16 (vectorized) ----------------
__global__ void cvt_kernel(const float* __restrict__ src, ushort4* __restrict__ dst, int n4) {
  int i = blockIdx.x * blockDim.x + threadIdx.x;
  if (i < n4) {
    float4 v = reinterpret_cast<const float4*>(src)[i];
    ushort4 o;
    o.x = f2bf(v.x); o.y = f2bf(v.y); o.z = f2bf(v.z); o.w = f2bf(v.w);
    dst[i] = o;
  }
}

// ---------------- 6-phase GEMM, 32x32x16 core: C = A * B^T ----------------
// ROUND-10: identical sync skeleton to r9 (phases, barriers, vmcnt table,
// staging slots, LDS layout, XOR swizzle, per-phase read counts ALL
// unchanged) -- only the MFMA shape changes 16x16x32 -> 32x32x16:
//   32 MFMA/tile/wave instead of 64 (8.07cyc vs 2x4.85; half issue slots).
// Fragments (verified pattern family; C/D layout m74/m101-measured):
//   A frag (m,kk,ks): lane holds A[row][k], row = base + (l&31),
//     k = kk*32 + ks*16 + (l>>5)*8 + e, e in [0,8) -> byte col =
//     (kk*64 + ks*32 + (l>>5)*16) ^ ((row&7)<<4)   [same b128 reads]
//   B frag (nh,kk,ks): row = nh*128 + wn*32 + (l&31), same col math.
//   C/D: col = lane&31, row = (reg&3) + 8*(reg>>2) + 4*(lane>>5).
// acc: f32x16 [2*M32][2] (M32 = BM/128) = 128 (BM256) / 64 (BM128) VGPR.
// Phase clusters: P0..P3 = M32*2 MFMA each, P4/P5 = 2 clusters each.
// EP: 0 = bf16 out + bias[col]; 1 = f32 out * scale; 2 = f32 out;
//     3 = bf16 out + bias[ROW]  (Vt = Wv * x^T + bv)
template <int BM_, int EP>
__global__ __launch_bounds__(512, 2) void gemm8(
    const unsigned short* __restrict__ A, const unsigned short* __restrict__ Bm,
    void* __restrict__ Cp, const float* __restrict__ bias,
    int lda, int ldb, int ldc, int NT, float scale,
    long zsA, long zsB, long zsC) {
  constexpr int BN_ = 256;
  constexpr int BK = 64;                 // elements (128 bytes)
  constexpr int RA = BM_ / 128;          // stage loads per A-half per wave
  constexpr int HALF_A = (BM_ / 2) * 128;  // bytes
  constexpr int HALF_B = 128 * 128;
  constexpr int ATILE = BM_ * 128;
  constexpr int BTILE = BN_ * 128;
  constexpr int M32 = BM_ / 128;         // 32-row A reps per quadrant (2 or 1)
  constexpr int VPRO = (BM_ == 256) ? 4 : 3;
  constexpr int V_P0 = (BM_ == 256) ? 4 : 2;
  constexpr int V_P3 = (BM_ == 256) ? 8 : 6;
  constexpr int V_P5 = (BM_ == 256) ? 4 : 3;
  constexpr int VD_P0 = (BM_ == 256) ? 2 : 1;

  __shared__ alignas(16) char lds[(ATILE + BTILE) * 2];

  const int tid = threadIdx.x;
  const int l = tid & 63;
  const int w = tid >> 6;   // 0..7
  const int wm = w >> 2;    // 0..1
  const int wn = w & 3;     // 0..3

  // bijective XCD-chunked swizzle (nwg % 8 == 0 for all our grids)
  const int gx = gridDim.x;
  const int nwg = gridDim.x * gridDim.y;
  int n = blockIdx.y * gx + blockIdx.x;
  int n2 = (n & 7) * (nwg >> 3) + (n >> 3);
  const int tileM = (n2 / gx) * BM_;
  const int tileN = (n2 % gx) * BN_;

  const int z = blockIdx.z;
  const unsigned short* Ab = A + (size_t)z * zsA;
  const unsigned short* Bb = Bm + (size_t)z * zsB;

  // staging: per-lane pre-swizzled global col; linear LDS dest (wave-uniform base)
  const int srow = l >> 3;                       // 0..7 within 8-row wave chunk
  const int scol = (((l & 7) ^ srow) * 16);      // swizzled byte col within 128B row

  auto stageA = [&](int buf, int t, int h) {
#pragma unroll
    for (int r = 0; r < RA; ++r) {
      int row = h * (BM_ / 2) + r * 64 + w * 8 + srow;
      const char* g = (const char*)(Ab + (size_t)(tileM + row) * lda + t * BK) + scol;
      char* d = lds + buf * (ATILE + BTILE) + h * HALF_A + r * 8192 + w * 1024;
      __builtin_amdgcn_global_load_lds(
          (const __attribute__((address_space(1))) void*)g,
          (__attribute__((address_space(3))) void*)d, 16, 0, 0);
    }
  };
  auto stageB = [&](int buf, int t, int h) {
#pragma unroll
    for (int r = 0; r < 2; ++r) {
      int row = h * 128 + r * 64 + w * 8 + srow;
      const char* g = (const char*)(Bb + (size_t)(tileN + row) * ldb + t * BK) + scol;
      char* d = lds + buf * (ATILE + BTILE) + ATILE + h * HALF_B + r * 8192 + w * 1024;
      __builtin_amdgcn_global_load_lds(
          (const __attribute__((address_space(1))) void*)g,
          (__attribute__((address_space(3))) void*)d, 16, 0, 0);
    }
  };

  f32x16 acc[2 * M32][2];
#pragma unroll
  for (int m = 0; m < 2 * M32; ++m)
#pragma unroll
    for (int nn = 0; nn < 2; ++nn)
#pragma unroll
      for (int e = 0; e < 16; ++e) acc[m][nn][e] = 0.f;

  // fragment ds_read (same XOR swizzle as staging); 32x32x16 operand layout
  auto rdA32 = [&](int buf, int mh, int m, int kk, int ks) -> bf16x8 {
    int row = mh * (BM_ / 2) + wm * (BM_ / 4) + m * 32 + (l & 31);
    int col = (kk * 64 + ks * 32 + ((l >> 5) * 16)) ^ ((row & 7) << 4);
    return *reinterpret_cast<const bf16x8*>(lds + buf * (ATILE + BTILE) + row * 128 + col);
  };
  auto rdB32 = [&](int buf, int nh, int kk, int ks) -> bf16x8 {
    int row = nh * 128 + wn * 32 + (l & 31);
    int col = (kk * 64 + ks * 32 + ((l >> 5) * 16)) ^ ((row & 7) << 4);
    return *reinterpret_cast<const bf16x8*>(lds + buf * (ATILE + BTILE) + ATILE + row * 128 + col);
  };

  bf16x8 avA[M32][2], avB[M32][2];  // rotating A sets: [m][ks]
  bf16x8 bvv[2][2][2];              // [nh][kk][ks] -- all four B sets held per tile

  auto rdAset = [&](int buf, int mh, int kk, bf16x8 (&dst)[M32][2]) {
#pragma unroll
    for (int m = 0; m < M32; ++m)
#pragma unroll
      for (int ks = 0; ks < 2; ++ks) dst[m][ks] = rdA32(buf, mh, m, kk, ks);
  };
  auto rdBset = [&](int buf, int nh, int kk) {
#pragma unroll
    for (int ks = 0; ks < 2; ++ks) bvv[nh][kk][ks] = rdB32(buf, nh, kk, ks);
  };
  auto mfc = [&](bf16x8 (&av)[M32][2], int mh, int nh, int kk) {
    __builtin_amdgcn_s_setprio(1);
#pragma unroll
    for (int m = 0; m < M32; ++m)
#pragma unroll
      for (int ks = 0; ks < 2; ++ks)
        acc[mh * M32 + m][nh] = __builtin_amdgcn_mfma_f32_32x32x16_bf16(
            av[m][ks], bvv[nh][kk][ks], acc[mh * M32 + m][nh], 0, 0, 0);
    __builtin_amdgcn_s_setprio(0);
  };

  // prologue: stage tile 0 (order A0,B0,B1,A1); guard A0,B0 resident
  stageA(0, 0, 0);
  stageB(0, 0, 0);
  stageB(0, 0, 1);
  stageA(0, 0, 1);
  waitvm<VPRO>();
  BARRIER();

  for (int t = 0; t < NT - 1; ++t) {
    const int buf = t & 1, nb = buf ^ 1;
    // P0: (0,0,k0); stage A0'; guard B1(t) for P1's reads
    rdAset(buf, 0, 0, avA); rdBset(buf, 0, 0);
    stageA(nb, t + 1, 0); waitvm<V_P0>(); BARRIER();
    mfc(avA, 0, 0, 0);
    // P1: (0,1,k0); stage B0'
    rdBset(buf, 1, 0);
    stageB(nb, t + 1, 0); BARRIER();
    mfc(avA, 0, 1, 0);
    // P2: (0,1,k1); stage B1'
    rdAset(buf, 0, 1, avB); rdBset(buf, 1, 1);
    stageB(nb, t + 1, 1); BARRIER();
    mfc(avB, 0, 1, 1);
    // P3: (0,0,k1); stage A1'; guard A1(t) for P4's reads
    rdBset(buf, 0, 1);
    stageA(nb, t + 1, 1); waitvm<V_P3>(); BARRIER();
    mfc(avB, 0, 0, 1);
    // P4: (1,0,k1)+(1,1,k1)
    rdAset(buf, 1, 1, avA);
    BARRIER();
    mfc(avA, 1, 0, 1); mfc(avA, 1, 1, 1);
    // P5: (1,1,k0)+(1,0,k0); guard A0',B0' for t+1.P0
    rdAset(buf, 1, 0, avB);
    waitvm<V_P5>(); BARRIER();
    mfc(avB, 1, 1, 0); mfc(avB, 1, 0, 0);
  }
  {  // peeled last tile: no staging; drain counted waits (same guard rule)
    const int buf = (NT - 1) & 1;
    rdAset(buf, 0, 0, avA); rdBset(buf, 0, 0); waitvm<VD_P0>(); BARRIER();
    mfc(avA, 0, 0, 0);
    rdBset(buf, 1, 0); BARRIER();
    mfc(avA, 0, 1, 0);
    rdAset(buf, 0, 1, avB); rdBset(buf, 1, 1); BARRIER();
    mfc(avB, 0, 1, 1);
    rdBset(buf, 0, 1); waitvm<0>(); BARRIER();
    mfc(avB, 0, 0, 1);
    rdAset(buf, 1, 1, avA); BARRIER();
    mfc(avA, 1, 0, 1); mfc(avA, 1, 1, 1);
    rdAset(buf, 1, 0, avB); BARRIER();
    mfc(avB, 1, 1, 0); mfc(avB, 1, 0, 0);
  }

  // epilogue: 32x32 C/D layout (m74/m101-verified):
  //   col = lane&31, row = (reg&3) + 8*(reg>>2) + 4*(lane>>5)
  const int lc = l & 31;
  const int lr4 = (l >> 5) * 4;
#pragma unroll
  for (int mh = 0; mh < 2; ++mh) {
#pragma unroll
    for (int m = 0; m < M32; ++m) {
#pragma unroll
      for (int nh = 0; nh < 2; ++nh) {
        f32x16 v = acc[mh * M32 + m][nh];
        int grb = tileM + mh * (BM_ / 2) + wm * (BM_ / 4) + m * 32 + lr4;
        int gc = tileN + nh * 128 + wn * 32 + lc;
#pragma unroll
        for (int reg = 0; reg < 16; ++reg) {
          int gr = grb + (reg & 3) + 8 * (reg >> 2);
          if constexpr (EP == 0 || EP == 3) {
            unsigned short* C = (unsigned short*)Cp + (size_t)z * zsC;
            float bb = (EP == 0) ? bias[gc] : bias[gr];
            C[(size_t)gr * ldc + gc] = f2bf(v[reg] + bb);
          } else {
            float* C = (float*)Cp + (size_t)z * zsC;
            C[(size_t)gr * ldc + gc] = (EP == 1) ? v[reg] * scale : v[reg];
          }
        }
      }
    }
  }
}

// ---------------- row softmax: fp32 [8192 x 2048] -> bf16 P ----------------
__global__ __launch_bounds__(256) void softmax_kernel(const float* __restrict__ Sb,
                                                      unsigned short* __restrict__ P) {
  const size_t row = blockIdx.x;
  const float* sp = Sb + row * S_LEN;
  const int t = threadIdx.x;
  const int wid = t >> 6, lane = t & 63;
  float4 v0 = reinterpret_cast<const float4*>(sp)[t * 2];
  float4 v1 = reinterpret_cast<const float4*>(sp)[t * 2 + 1];
  float s[8] = {v0.x, v0.y, v0.z, v0.w, v1.x, v1.y, v1.z, v1.w};
  float mx = s[0];
#pragma unroll
  for (int i = 1; i < 8; ++i) mx = fmaxf(mx, s[i]);
#pragma unroll
  for (int o = 32; o > 0; o >>= 1) mx = fmaxf(mx, __shfl_xor(mx, o));
  __shared__ float redm[4];
  __shared__ float reds[4];
  if (lane == 0) redm[wid] = mx;
  __syncthreads();
  mx = fmaxf(fmaxf(redm[0], redm[1]), fmaxf(redm[2], redm[3]));
  float e[8];
  float sum = 0.f;
#pragma unroll
  for (int i = 0; i < 8; ++i) { e[i] = __expf(s[i] - mx); sum += e[i]; }
#pragma unroll
  for (int o = 32; o > 0; o >>= 1) sum += __shfl_xor(sum, o);
  if (lane == 0) reds[wid] = sum;
  __syncthreads();
  sum = reds[0] + reds[1] + reds[2] + reds[3];
  float inv = 1.0f / sum;
  ushort4 o0, o1;
  o0.x = f2bf(e[0] * inv); o0.y = f2bf(e[1] * inv); o0.z = f2bf(e[2] * inv); o0.w = f2bf(e[3] * inv);
  o1.x = f2bf(e[4] * inv); o1.y = f2bf(e[5] * inv); o1.z = f2bf(e[6] * inv); o1.w = f2bf(e[7] * inv);
  ushort4* dp = reinterpret_cast<ushort4*>(P + row * S_LEN);
  dp[t * 2] = o0;
  dp[t * 2 + 1] = o1;
}

extern "C" void kernel_launch(void* const* d_in, const int* in_sizes, int n_in,
                              void* d_out, int out_size, void* d_ws, size_t ws_size,
                              hipStream_t stream) {
  (void)in_sizes; (void)n_in; (void)out_size;
  const float* x = (const float*)d_in[0];
  const float* Wq = (const float*)d_in[1];
  const float* bq = (const float*)d_in[2];
  const float* Wk = (const float*)d_in[3];
  const float* bk = (const float*)d_in[4];
  const float* Wv = (const float*)d_in[5];
  const float* bv = (const float*)d_in[6];
  float* out = (float*)d_out;

  // workspace layout (bytes), total ~135 MB:
  //   xb   bf16 [8192][1024]    @ 0       (16 MB)  -- alive until Vt-GEMM done
  //   Wqkb bf16 [2048][1024]    @ 16 MB   (4 MB)   -- [Wq;Wk]
  //   Wvb  bf16 [1024][1024]    @ 20 MB   (2 MB)
  //   bqk  f32  [2048]          @ 22 MB   (8 KB)
  //   QKb  bf16 [8192][2048]    @ 23 MB   (32 MB)  -- reused as P after scores
  //   Sb   f32  [4][2048][2048] @ 55 MB   (64 MB)
  //   Vt   bf16 [4][1024][2048] @ 119 MB  (16 MB)
  if (ws_size < 141557760ull) return;
  char* ws = (char*)d_ws;
  unsigned short* xb   = (unsigned short*)(ws);
  unsigned short* Wqkb = (unsigned short*)(ws + 16777216);
  unsigned short* Wvb  = (unsigned short*)(ws + 20971520);
  float*          bqk  = (float*)(ws + 23068672);
  unsigned short* QKb  = (unsigned short*)(ws + 24117248);
  float*          Sb   = (float*)(ws + 57671680);
  unsigned short* Vt   = (unsigned short*)(ws + 124780544);
  unsigned short* P    = QKb;  // alias: QKb dead after scores GEMM

  // 1) converts to bf16 (+ fused weight concat [Wq;Wk])
  cvt_kernel<<<dim3(MROWS * DMODEL / 4 / 256), 256, 0, stream>>>(x, (ushort4*)xb, MROWS * DMODEL / 4);
  cvt_kernel<<<dim3(1024), 256, 0, stream>>>(Wq, (ushort4*)Wqkb, DMODEL * DMODEL / 4);
  cvt_kernel<<<dim3(1024), 256, 0, stream>>>(Wk, (ushort4*)(Wqkb + 1048576), DMODEL * DMODEL / 4);
  cvt_kernel<<<dim3(1024), 256, 0, stream>>>(Wv, (ushort4*)Wvb, DMODEL * DMODEL / 4);
  hipMemcpyAsync(bqk, bq, 4096, hipMemcpyDeviceToDevice, stream);
  hipMemcpyAsync(bqk + 1024, bk, 4096, hipMemcpyDeviceToDevice, stream);

  // 2) QK projection: [8192x2048] = x * [Wq;Wk]^T + bqk  (grid 256 = 1 round)
  gemm8<256, 0><<<dim3(8, 32, 1), 512, 0, stream>>>(
      xb, Wqkb, QKb, bqk, 1024, 1024, 2048, 16, 1.f, 0, 0, 0);

  // 3) Vt = Wv * x^T + bv (per batch): grid (8,8,4) = 256 half-size blocks
  gemm8<128, 3><<<dim3(8, 8, 4), 512, 0, stream>>>(
      Wvb, xb, Vt, bv, 1024, 1024, 2048, 16, 1.f,
      0, (long)S_LEN * DMODEL, (long)DMODEL * S_LEN);

  // 4) scores: Sb = Q * K^T * 0.125 (per batch M=N=2048, K=1024)
  gemm8<256, 1><<<dim3(8, 8, 4), 512, 0, stream>>>(
      QKb, QKb + 1024, Sb, nullptr, 2048, 2048, 2048, 16, 0.125f,
      (long)S_LEN * 2048, (long)S_LEN * 2048, (long)S_LEN * S_LEN);

  // 5) row softmax -> bf16 P (aliases QKb)
  softmax_kernel<<<dim3(MROWS), 256, 0, stream>>>(Sb, P);

  // 6) out = P * Vt^T (per batch M=2048, N=1024, K=2048; grid 256 = 1 round)
  gemm8<128, 2><<<dim3(4, 16, 4), 512, 0, stream>>>(
      P, Vt, out, nullptr, 2048, 2048, 1024, 32, 1.f,
      (long)S_LEN * S_LEN, (long)DMODEL * S_LEN, (long)S_LEN * DMODEL);
}

// Round 12
// 167.674 us; speedup vs baseline: 1.1137x; 1.1137x over previous
//
#include <hip/hip_runtime.h>
#include <stdint.h>

#define S_LEN 2048
#define DMODEL 1024
#define NBATCH 4
#define MROWS (NBATCH * S_LEN)  // 8192

typedef __bf16 bf16x8 __attribute__((ext_vector_type(8)));
typedef float f32x4 __attribute__((ext_vector_type(4)));

__device__ __forceinline__ unsigned short f2bf(float f) {
  unsigned int x = __builtin_bit_cast(unsigned int, f);
  x += 0x7FFFu + ((x >> 16) & 1u);
  return (unsigned short)(x >> 16);
}

template <int N>
__device__ __forceinline__ void waitvm() {
  static_assert(N <= 8, "vmcnt range");
  if constexpr (N < 0) {}
  else if constexpr (N == 0) asm volatile("s_waitcnt vmcnt(0)" ::: "memory");
  else if constexpr (N == 1) asm volatile("s_waitcnt vmcnt(1)" ::: "memory");
  else if constexpr (N == 2) asm volatile("s_waitcnt vmcnt(2)" ::: "memory");
  else if constexpr (N == 3) asm volatile("s_waitcnt vmcnt(3)" ::: "memory");
  else if constexpr (N == 4) asm volatile("s_waitcnt vmcnt(4)" ::: "memory");
  else if constexpr (N == 5) asm volatile("s_waitcnt vmcnt(5)" ::: "memory");
  else if constexpr (N == 6) asm volatile("s_waitcnt vmcnt(6)" ::: "memory");
  else if constexpr (N == 7) asm volatile("s_waitcnt vmcnt(7)" ::: "memory");
  else asm volatile("s_waitcnt vmcnt(8)" ::: "memory");
}
#define BARRIER() do { __builtin_amdgcn_s_barrier(); asm volatile("" ::: "memory"); } while (0)
// m201 pattern (+rule #18): drain LDS reads once, pin MFMA below the wait.
#define LGKM0() do { asm volatile("s_waitcnt lgkmcnt(0)" ::: "memory"); \
                     __builtin_amdgcn_sched_barrier(0); } while (0)

// ---------------- convert f32 -> bf16 (vectorized) ----------------
__global__ void cvt_kernel(const float* __restrict__ src, ushort4* __restrict__ dst, int n4) {
  int i = blockIdx.x * blockDim.x + threadIdx.x;
  if (i < n4) {
    float4 v = reinterpret_cast<const float4*>(src)[i];
    ushort4 o;
    o.x = f2bf(v.x); o.y = f2bf(v.y); o.z = f2bf(v.z); o.w = f2bf(v.w);
    dst[i] = o;
  }
}

// ---------------- fused weight/bias prep: Wq,Wk->Wqkb, Wv->Wvb, bq,bk->bqk ----------------
__global__ void prep_kernel(const float* __restrict__ Wq, const float* __restrict__ Wk,
                            const float* __restrict__ Wv, const float* __restrict__ bq,
                            const float* __restrict__ bk, ushort4* __restrict__ Wqkb,
                            ushort4* __restrict__ Wvb, float4* __restrict__ bqk) {
  const int NW = DMODEL * DMODEL / 4;  // 262144 ushort4 per weight matrix
  int i = blockIdx.x * blockDim.x + threadIdx.x;
  float4 v;
  if (i < NW) v = reinterpret_cast<const float4*>(Wq)[i];
  else if (i < 2 * NW) v = reinterpret_cast<const float4*>(Wk)[i - NW];
  else v = reinterpret_cast<const float4*>(Wv)[i - 2 * NW];
  ushort4 o;
  o.x = f2bf(v.x); o.y = f2bf(v.y); o.z = f2bf(v.z); o.w = f2bf(v.w);
  if (i < 2 * NW) Wqkb[i] = o;
  else Wvb[i - 2 * NW] = o;
  if (i < 512) bqk[i] = (i < 256) ? reinterpret_cast<const float4*>(bq)[i]
                                  : reinterpret_cast<const float4*>(bk)[i - 256];
}

// ---------------- 6-phase balanced GEMM (r9 skeleton + lgkm fence + unroll): C = A * B^T ----
// 16x16x32 core (r10's 32x32 reverted: [row][128B] layout makes 32-lane
// column reads an unavoidable 4-way bank conflict; 16-lane groups are 2-way
// = free). Sync skeleton, vmcnt table, staging slots, XOR swizzle identical
// to r9 (verified 0 bank conflicts, absmax 0.078).
// NEW: (a) LGKM0 fence after each pre-MFMA barrier -- drains all ds_reads
// once instead of compiler-placed per-fragment lgkmcnt(N) mid-cluster
// stalls; (b) NT is a template param + #pragma unroll 2 (m201: 2 K-tiles
// per iteration) so the scheduler pipelines across phase boundaries.
// EP: 0 = bf16 out + bias[col]; 1 = f32 out * scale; 2 = f32 out;
//     3 = bf16 out + bias[ROW]  (Vt = Wv * x^T + bv)
template <int BM_, int EP, int NT>
__global__ __launch_bounds__(512, 2) void gemm8(
    const unsigned short* __restrict__ A, const unsigned short* __restrict__ Bm,
    void* __restrict__ Cp, const float* __restrict__ bias,
    int lda, int ldb, int ldc, float scale,
    long zsA, long zsB, long zsC) {
  constexpr int BN_ = 256;
  constexpr int BK = 64;                 // elements (128 bytes)
  constexpr int RA = BM_ / 128;          // stage loads per A-half per wave
  constexpr int HALF_A = (BM_ / 2) * 128;  // bytes
  constexpr int HALF_B = 128 * 128;
  constexpr int ATILE = BM_ * 128;
  constexpr int BTILE = BN_ * 128;
  constexpr int MREP = BM_ / 32;         // 8 or 4
  constexpr int MQ = MREP / 2;           // A frags per half (4 or 2)
  constexpr int VPRO = (BM_ == 256) ? 4 : 3;
  constexpr int V_P0 = (BM_ == 256) ? 4 : 2;
  constexpr int V_P3 = (BM_ == 256) ? 8 : 6;
  constexpr int V_P5 = (BM_ == 256) ? 4 : 3;
  constexpr int VD_P0 = (BM_ == 256) ? 2 : 1;

  __shared__ alignas(16) char lds[(ATILE + BTILE) * 2];

  const int tid = threadIdx.x;
  const int l = tid & 63;
  const int w = tid >> 6;   // 0..7
  const int wm = w >> 2;    // 0..1
  const int wn = w & 3;     // 0..3

  // bijective XCD-chunked swizzle (nwg % 8 == 0 for all our grids)
  const int gx = gridDim.x;
  const int nwg = gridDim.x * gridDim.y;
  int n = blockIdx.y * gx + blockIdx.x;
  int n2 = (n & 7) * (nwg >> 3) + (n >> 3);
  const int tileM = (n2 / gx) * BM_;
  const int tileN = (n2 % gx) * BN_;

  const int z = blockIdx.z;
  const unsigned short* Ab = A + (size_t)z * zsA;
  const unsigned short* Bb = Bm + (size_t)z * zsB;

  // staging: per-lane pre-swizzled global col; linear LDS dest (wave-uniform base)
  const int srow = l >> 3;                       // 0..7 within 8-row wave chunk
  const int scol = (((l & 7) ^ srow) * 16);      // swizzled byte col within 128B row

  auto stageA = [&](int buf, int t, int h) {
#pragma unroll
    for (int r = 0; r < RA; ++r) {
      int row = h * (BM_ / 2) + r * 64 + w * 8 + srow;
      const char* g = (const char*)(Ab + (size_t)(tileM + row) * lda + t * BK) + scol;
      char* d = lds + buf * (ATILE + BTILE) + h * HALF_A + r * 8192 + w * 1024;
      __builtin_amdgcn_global_load_lds(
          (const __attribute__((address_space(1))) void*)g,
          (__attribute__((address_space(3))) void*)d, 16, 0, 0);
    }
  };
  auto stageB = [&](int buf, int t, int h) {
#pragma unroll
    for (int r = 0; r < 2; ++r) {
      int row = h * 128 + r * 64 + w * 8 + srow;
      const char* g = (const char*)(Bb + (size_t)(tileN + row) * ldb + t * BK) + scol;
      char* d = lds + buf * (ATILE + BTILE) + ATILE + h * HALF_B + r * 8192 + w * 1024;
      __builtin_amdgcn_global_load_lds(
          (const __attribute__((address_space(1))) void*)g,
          (__attribute__((address_space(3))) void*)d, 16, 0, 0);
    }
  };

  f32x4 acc[MREP][4];
#pragma unroll
  for (int m = 0; m < MREP; ++m)
#pragma unroll
    for (int nn = 0; nn < 4; ++nn) acc[m][nn] = f32x4{0.f, 0.f, 0.f, 0.f};

  // fragment ds_read (same XOR swizzle as staging)
  const int frow = l & 15;
  auto rdA = [&](int buf, int mh, int m, int kk) -> bf16x8 {
    int row = mh * (BM_ / 2) + wm * (BM_ / 4) + m * 16 + frow;
    int col = (kk * 64 + ((l >> 4) * 16)) ^ ((row & 7) << 4);
    return *reinterpret_cast<const bf16x8*>(lds + buf * (ATILE + BTILE) + row * 128 + col);
  };
  auto rdB = [&](int buf, int nh, int nn, int kk) -> bf16x8 {
    int row = nh * 128 + wn * 32 + nn * 16 + frow;
    int col = (kk * 64 + ((l >> 4) * 16)) ^ ((row & 7) << 4);
    return *reinterpret_cast<const bf16x8*>(lds + buf * (ATILE + BTILE) + ATILE + row * 128 + col);
  };

  bf16x8 avA[MQ], avB[MQ];   // rotating A half-kk sets
  bf16x8 bvv[2][2][2];       // [nh][kk][nn] -- all four B sets held per tile

  auto rdAset = [&](int buf, int mh, int kk, bf16x8 (&dst)[MQ]) {
#pragma unroll
    for (int m = 0; m < MQ; ++m) dst[m] = rdA(buf, mh, m, kk);
  };
  auto rdBset = [&](int buf, int nh, int kk) {
#pragma unroll
    for (int nn = 0; nn < 2; ++nn) bvv[nh][kk][nn] = rdB(buf, nh, nn, kk);
  };
  auto mf8 = [&](bf16x8 (&av)[MQ], int mh, int nh, int kk) {
    __builtin_amdgcn_s_setprio(1);
#pragma unroll
    for (int m = 0; m < MQ; ++m)
#pragma unroll
      for (int nn = 0; nn < 2; ++nn)
        acc[mh * MQ + m][nh * 2 + nn] = __builtin_amdgcn_mfma_f32_16x16x32_bf16(
            av[m], bvv[nh][kk][nn], acc[mh * MQ + m][nh * 2 + nn], 0, 0, 0);
    __builtin_amdgcn_s_setprio(0);
  };

  // prologue: stage tile 0 (order A0,B0,B1,A1); guard A0,B0 resident
  stageA(0, 0, 0);
  stageB(0, 0, 0);
  stageB(0, 0, 1);
  stageA(0, 0, 1);
  waitvm<VPRO>();
  BARRIER();

#pragma unroll 2
  for (int t = 0; t < NT - 1; ++t) {
    const int buf = t & 1, nb = buf ^ 1;
    // P0: (0,0,k0); stage A0'; guard B1(t) for P1's reads
    rdAset(buf, 0, 0, avA); rdBset(buf, 0, 0);
    stageA(nb, t + 1, 0); waitvm<V_P0>(); BARRIER(); LGKM0();
    mf8(avA, 0, 0, 0);
    // P1: (0,1,k0); stage B0'
    rdBset(buf, 1, 0);
    stageB(nb, t + 1, 0); BARRIER(); LGKM0();
    mf8(avA, 0, 1, 0);
    // P2: (0,1,k1); stage B1'
    rdAset(buf, 0, 1, avB); rdBset(buf, 1, 1);
    stageB(nb, t + 1, 1); BARRIER(); LGKM0();
    mf8(avB, 0, 1, 1);
    // P3: (0,0,k1); stage A1'; guard A1(t) for P4's reads
    rdBset(buf, 0, 1);
    stageA(nb, t + 1, 1); waitvm<V_P3>(); BARRIER(); LGKM0();
    mf8(avB, 0, 0, 1);
    // P4: (1,0,k1)+(1,1,k1)
    rdAset(buf, 1, 1, avA);
    BARRIER(); LGKM0();
    mf8(avA, 1, 0, 1); mf8(avA, 1, 1, 1);
    // P5: (1,1,k0)+(1,0,k0); guard A0',B0' for t+1.P0
    rdAset(buf, 1, 0, avB);
    waitvm<V_P5>(); BARRIER(); LGKM0();
    mf8(avB, 1, 1, 0); mf8(avB, 1, 0, 0);
  }
  {  // peeled last tile: no staging; drain counted waits (same guard rule)
    const int buf = (NT - 1) & 1;
    rdAset(buf, 0, 0, avA); rdBset(buf, 0, 0); waitvm<VD_P0>(); BARRIER(); LGKM0();
    mf8(avA, 0, 0, 0);
    rdBset(buf, 1, 0); BARRIER(); LGKM0();
    mf8(avA, 0, 1, 0);
    rdAset(buf, 0, 1, avB); rdBset(buf, 1, 1); BARRIER(); LGKM0();
    mf8(avB, 0, 1, 1);
    rdBset(buf, 0, 1); waitvm<0>(); BARRIER(); LGKM0();
    mf8(avB, 0, 0, 1);
    rdAset(buf, 1, 1, avA); BARRIER(); LGKM0();
    mf8(avA, 1, 0, 1); mf8(avA, 1, 1, 1);
    rdAset(buf, 1, 0, avB); BARRIER(); LGKM0();
    mf8(avB, 1, 1, 0); mf8(avB, 1, 0, 0);
  }

  // epilogue: C/D layout (m89): col = lane&15, row = (lane>>4)*4 + j
  const int lr = (l >> 4) * 4;
  const int lc = l & 15;
#pragma unroll
  for (int mh = 0; mh < 2; ++mh) {
#pragma unroll
    for (int m = 0; m < MQ; ++m) {
#pragma unroll
      for (int nh = 0; nh < 2; ++nh) {
#pragma unroll
        for (int nn = 0; nn < 2; ++nn) {
          int gr = tileM + mh * (BM_ / 2) + wm * (BM_ / 4) + m * 16 + lr;
          int gc = tileN + nh * 128 + wn * 32 + nn * 16 + lc;
          f32x4 v = acc[mh * MQ + m][nh * 2 + nn];
          if constexpr (EP == 0 || EP == 3) {
            unsigned short* C = (unsigned short*)Cp + (size_t)z * zsC;
#pragma unroll
            for (int j = 0; j < 4; ++j) {
              float bb = (EP == 0) ? bias[gc] : bias[gr + j];
              C[(size_t)(gr + j) * ldc + gc] = f2bf(v[j] + bb);
            }
          } else {
            float* C = (float*)Cp + (size_t)z * zsC;
#pragma unroll
            for (int j = 0; j < 4; ++j)
              C[(size_t)(gr + j) * ldc + gc] = (EP == 1) ? v[j] * scale : v[j];
          }
        }
      }
    }
  }
}

// ---------------- row softmax: fp32 [8192 x 2048] -> bf16 P ----------------
__global__ __launch_bounds__(256) void softmax_kernel(const float* __restrict__ Sb,
                                                      unsigned short* __restrict__ P) {
  const size_t row = blockIdx.x;
  const float* sp = Sb + row * S_LEN;
  const int t = threadIdx.x;
  const int wid = t >> 6, lane = t & 63;
  float4 v0 = reinterpret_cast<const float4*>(sp)[t * 2];
  float4 v1 = reinterpret_cast<const float4*>(sp)[t * 2 + 1];
  float s[8] = {v0.x, v0.y, v0.z, v0.w, v1.x, v1.y, v1.z, v1.w};
  float mx = s[0];
#pragma unroll
  for (int i = 1; i < 8; ++i) mx = fmaxf(mx, s[i]);
#pragma unroll
  for (int o = 32; o > 0; o >>= 1) mx = fmaxf(mx, __shfl_xor(mx, o));
  __shared__ float redm[4];
  __shared__ float reds[4];
  if (lane == 0) redm[wid] = mx;
  __syncthreads();
  mx = fmaxf(fmaxf(redm[0], redm[1]), fmaxf(redm[2], redm[3]));
  float e[8];
  float sum = 0.f;
#pragma unroll
  for (int i = 0; i < 8; ++i) { e[i] = __expf(s[i] - mx); sum += e[i]; }
#pragma unroll
  for (int o = 32; o > 0; o >>= 1) sum += __shfl_xor(sum, o);
  if (lane == 0) reds[wid] = sum;
  __syncthreads();
  sum = reds[0] + reds[1] + reds[2] + reds[3];
  float inv = 1.0f / sum;
  ushort4 o0, o1;
  o0.x = f2bf(e[0] * inv); o0.y = f2bf(e[1] * inv); o0.z = f2bf(e[2] * inv); o0.w = f2bf(e[3] * inv);
  o1.x = f2bf(e[4] * inv); o1.y = f2bf(e[5] * inv); o1.z = f2bf(e[6] * inv); o1.w = f2bf(e[7] * inv);
  ushort4* dp = reinterpret_cast<ushort4*>(P + row * S_LEN);
  dp[t * 2] = o0;
  dp[t * 2 + 1] = o1;
}

extern "C" void kernel_launch(void* const* d_in, const int* in_sizes, int n_in,
                              void* d_out, int out_size, void* d_ws, size_t ws_size,
                              hipStream_t stream) {
  (void)in_sizes; (void)n_in; (void)out_size;
  const float* x = (const float*)d_in[0];
  const float* Wq = (const float*)d_in[1];
  const float* bq = (const float*)d_in[2];
  const float* Wk = (const float*)d_in[3];
  const float* bk = (const float*)d_in[4];
  const float* Wv = (const float*)d_in[5];
  const float* bv = (const float*)d_in[6];
  float* out = (float*)d_out;

  // workspace layout (bytes), total ~135 MB:
  //   xb   bf16 [8192][1024]    @ 0       (16 MB)
  //   Wqkb bf16 [2048][1024]    @ 16 MB   (4 MB)   -- [Wq;Wk]
  //   Wvb  bf16 [1024][1024]    @ 20 MB   (2 MB)
  //   bqk  f32  [2048]          @ 22 MB   (8 KB)
  //   QKb  bf16 [8192][2048]    @ 23 MB   (32 MB)  -- reused as P after scores
  //   Sb   f32  [4][2048][2048] @ 55 MB   (64 MB)
  //   Vt   bf16 [4][1024][2048] @ 119 MB  (16 MB)
  if (ws_size < 141557760ull) return;
  char* ws = (char*)d_ws;
  unsigned short* xb   = (unsigned short*)(ws);
  unsigned short* Wqkb = (unsigned short*)(ws + 16777216);
  unsigned short* Wvb  = (unsigned short*)(ws + 20971520);
  float*          bqk  = (float*)(ws + 23068672);
  unsigned short* QKb  = (unsigned short*)(ws + 24117248);
  float*          Sb   = (float*)(ws + 57671680);
  unsigned short* Vt   = (unsigned short*)(ws + 124780544);
  unsigned short* P    = QKb;  // alias: QKb dead after scores GEMM

  // 1) input cvt + fused weight/bias prep (2 launches, was 4 + 2 memcpy)
  cvt_kernel<<<dim3(MROWS * DMODEL / 4 / 256), 256, 0, stream>>>(x, (ushort4*)xb, MROWS * DMODEL / 4);
  prep_kernel<<<dim3(3 * DMODEL * DMODEL / 4 / 256), 256, 0, stream>>>(
      Wq, Wk, Wv, bq, bk, (ushort4*)Wqkb, (ushort4*)Wvb, (float4*)bqk);

  // 2) QK projection: [8192x2048] = x * [Wq;Wk]^T + bqk  (grid 256 = 1 round)
  gemm8<256, 0, 16><<<dim3(8, 32, 1), 512, 0, stream>>>(
      xb, Wqkb, QKb, bqk, 1024, 1024, 2048, 1.f, 0, 0, 0);

  // 3) Vt = Wv * x^T + bv (per batch): grid (8,8,4) = 256 half-size blocks
  gemm8<128, 3, 16><<<dim3(8, 8, 4), 512, 0, stream>>>(
      Wvb, xb, Vt, bv, 1024, 1024, 2048, 1.f,
      0, (long)S_LEN * DMODEL, (long)DMODEL * S_LEN);

  // 4) scores: Sb = Q * K^T * 0.125 (per batch M=N=2048, K=1024)
  gemm8<256, 1, 16><<<dim3(8, 8, 4), 512, 0, stream>>>(
      QKb, QKb + 1024, Sb, nullptr, 2048, 2048, 2048, 0.125f,
      (long)S_LEN * 2048, (long)S_LEN * 2048, (long)S_LEN * S_LEN);

  // 5) row softmax -> bf16 P (aliases QKb)
  softmax_kernel<<<dim3(MROWS), 256, 0, stream>>>(Sb, P);

  // 6) out = P * Vt^T (per batch M=2048, N=1024, K=2048; grid 256 = 1 round)
  gemm8<128, 2, 32><<<dim3(4, 16, 4), 512, 0, stream>>>(
      P, Vt, out, nullptr, 2048, 2048, 1024, 1.f,
      (long)S_LEN * S_LEN, (long)DMODEL * S_LEN, (long)S_LEN * DMODEL);
}

// Round 13
// 165.914 us; speedup vs baseline: 1.1255x; 1.0106x over previous
//
#include <hip/hip_runtime.h>
#include <stdint.h>

#define S_LEN 2048
#define DMODEL 1024
#define NBATCH 4
#define MROWS (NBATCH * S_LEN)  // 8192

typedef __bf16 bf16x8 __attribute__((ext_vector_type(8)));
typedef float f32x4 __attribute__((ext_vector_type(4)));

__device__ __forceinline__ unsigned short f2bf(float f) {
  unsigned int x = __builtin_bit_cast(unsigned int, f);
  x += 0x7FFFu + ((x >> 16) & 1u);
  return (unsigned short)(x >> 16);
}

template <int N>
__device__ __forceinline__ void waitvm() {
  static_assert(N <= 8, "vmcnt range");
  if constexpr (N < 0) {}
  else if constexpr (N == 0) asm volatile("s_waitcnt vmcnt(0)" ::: "memory");
  else if constexpr (N == 1) asm volatile("s_waitcnt vmcnt(1)" ::: "memory");
  else if constexpr (N == 2) asm volatile("s_waitcnt vmcnt(2)" ::: "memory");
  else if constexpr (N == 3) asm volatile("s_waitcnt vmcnt(3)" ::: "memory");
  else if constexpr (N == 4) asm volatile("s_waitcnt vmcnt(4)" ::: "memory");
  else if constexpr (N == 5) asm volatile("s_waitcnt vmcnt(5)" ::: "memory");
  else if constexpr (N == 6) asm volatile("s_waitcnt vmcnt(6)" ::: "memory");
  else if constexpr (N == 7) asm volatile("s_waitcnt vmcnt(7)" ::: "memory");
  else asm volatile("s_waitcnt vmcnt(8)" ::: "memory");
}
#define BARRIER() do { __builtin_amdgcn_s_barrier(); asm volatile("" ::: "memory"); } while (0)
// m201 pattern (+rule #18): drain LDS reads once, pin MFMA below the wait.
#define LGKM0() do { asm volatile("s_waitcnt lgkmcnt(0)" ::: "memory"); \
                     __builtin_amdgcn_sched_barrier(0); } while (0)

// ---------------- convert f32 -> bf16 (vectorized) ----------------
__global__ void cvt_kernel(const float* __restrict__ src, ushort4* __restrict__ dst, int n4) {
  int i = blockIdx.x * blockDim.x + threadIdx.x;
  if (i < n4) {
    float4 v = reinterpret_cast<const float4*>(src)[i];
    ushort4 o;
    o.x = f2bf(v.x); o.y = f2bf(v.y); o.z = f2bf(v.z); o.w = f2bf(v.w);
    dst[i] = o;
  }
}

// ---------------- fused weight/bias prep: Wq,Wk->Wqkb, Wv->Wvb, bq,bk->bqk ----------------
__global__ void prep_kernel(const float* __restrict__ Wq, const float* __restrict__ Wk,
                            const float* __restrict__ Wv, const float* __restrict__ bq,
                            const float* __restrict__ bk, ushort4* __restrict__ Wqkb,
                            ushort4* __restrict__ Wvb, float4* __restrict__ bqk) {
  const int NW = DMODEL * DMODEL / 4;  // 262144 ushort4 per weight matrix
  int i = blockIdx.x * blockDim.x + threadIdx.x;
  float4 v;
  if (i < NW) v = reinterpret_cast<const float4*>(Wq)[i];
  else if (i < 2 * NW) v = reinterpret_cast<const float4*>(Wk)[i - NW];
  else v = reinterpret_cast<const float4*>(Wv)[i - 2 * NW];
  ushort4 o;
  o.x = f2bf(v.x); o.y = f2bf(v.y); o.z = f2bf(v.z); o.w = f2bf(v.w);
  if (i < 2 * NW) Wqkb[i] = o;
  else Wvb[i - 2 * NW] = o;
  if (i < 512) bqk[i] = (i < 256) ? reinterpret_cast<const float4*>(bq)[i]
                                  : reinterpret_cast<const float4*>(bk)[i - 256];
}

// ---------------- 3-phase full-K GEMM: C = A * B^T ----------------
// ROUND-13: tile cost was ~6.4k cy at 6 phases (each phase = one latency
// quantum: vmcnt + barrier + lgkm drain, MFMA cluster only 39-78cy).
// Collapse to 3 phases/tile, full-K quadrant walk:
//   P_a: (A0,B0) k0+k1   reads A0 full-K (8 b128) + B0 full-K (4); 16 MFMA
//   P_b: (A0,B1)         reads B1 full-K (4);                      16 MFMA
//   P_c: (A1,B1)+(A1,B0) reads A1 full-K (8, overwrites A-set);    32 MFMA
// B0/B1 held full-tile; A rotates -- 64 operand VGPR (same as r12).
// Stage slots (t stages t+1): P_a: A0'+B0', P_b: B1', P_c: A1'.
// GUARD RULE (r7): reads at phase p guarded by vmcnt in phase p-1.
//   guard A0'B0'(t+1) [read P_a(t+1)] @ P_c(t): BM256 vm<4>, BM128 vm<3>
//   guard B1(t)       [read P_b(t)]   @ P_a(t): BM256 vm<6>, BM128 vm<4>
//   guard A1(t)       [read P_c(t)]   @ P_b(t): BM256 vm<6>, BM128 vm<5>
// Prologue: stage A0,B0,B1,A1; wait vm<4>/<3>. Drain: P_a vm<2>/<1>, P_b vm<0>.
// WAR: every overwritten region's last ds_read is LGKM0-drained >=3 barriers
// before its stage slot (audited half-by-half).
// Quadrant (mh,nh) reads EXACTLY the staged contiguous halves across waves:
//   A row = mh*(BM/2) + wm*(BM/4) + m*16 + frow
//   B row = nh*128    + wn*32     + nn*16 + frow
// LDS swizzle: 16B-slot index ^= (row&7) via pre-swizzled GLOBAL source
// (linear LDS dest, rule #21) and identically on ds_read. 16x16x32 core
// (32x32 is a structural 4-way bank conflict in [row][128B] layout -- r10).
// EP: 0 = bf16 out + bias[col]; 1 = f32 out * scale; 2 = f32 out;
//     3 = bf16 out + bias[ROW]  (Vt = Wv * x^T + bv)
template <int BM_, int EP, int NT>
__global__ __launch_bounds__(512, 2) void gemm8(
    const unsigned short* __restrict__ A, const unsigned short* __restrict__ Bm,
    void* __restrict__ Cp, const float* __restrict__ bias,
    int lda, int ldb, int ldc, float scale,
    long zsA, long zsB, long zsC) {
  constexpr int BN_ = 256;
  constexpr int BK = 64;                 // elements (128 bytes)
  constexpr int RA = BM_ / 128;          // stage loads per A-half per wave
  constexpr int HALF_A = (BM_ / 2) * 128;  // bytes
  constexpr int HALF_B = 128 * 128;
  constexpr int ATILE = BM_ * 128;
  constexpr int BTILE = BN_ * 128;
  constexpr int MREP = BM_ / 32;         // 8 or 4
  constexpr int MQ = MREP / 2;           // A frags per half (4 or 2)
  constexpr int VPRO = (BM_ == 256) ? 4 : 3;
  constexpr int W_PA = (BM_ == 256) ? 6 : 4;
  constexpr int W_PB = (BM_ == 256) ? 6 : 5;
  constexpr int W_PC = (BM_ == 256) ? 4 : 3;
  constexpr int VDA  = (BM_ == 256) ? 2 : 1;

  __shared__ alignas(16) char lds[(ATILE + BTILE) * 2];

  const int tid = threadIdx.x;
  const int l = tid & 63;
  const int w = tid >> 6;   // 0..7
  const int wm = w >> 2;    // 0..1
  const int wn = w & 3;     // 0..3

  // bijective XCD-chunked swizzle (nwg % 8 == 0 for all our grids)
  const int gx = gridDim.x;
  const int nwg = gridDim.x * gridDim.y;
  int n = blockIdx.y * gx + blockIdx.x;
  int n2 = (n & 7) * (nwg >> 3) + (n >> 3);
  const int tileM = (n2 / gx) * BM_;
  const int tileN = (n2 % gx) * BN_;

  const int z = blockIdx.z;
  const unsigned short* Ab = A + (size_t)z * zsA;
  const unsigned short* Bb = Bm + (size_t)z * zsB;

  // staging: per-lane pre-swizzled global col; linear LDS dest (wave-uniform base)
  const int srow = l >> 3;                       // 0..7 within 8-row wave chunk
  const int scol = (((l & 7) ^ srow) * 16);      // swizzled byte col within 128B row

  auto stageA = [&](int buf, int t, int h) {
#pragma unroll
    for (int r = 0; r < RA; ++r) {
      int row = h * (BM_ / 2) + r * 64 + w * 8 + srow;
      const char* g = (const char*)(Ab + (size_t)(tileM + row) * lda + t * BK) + scol;
      char* d = lds + buf * (ATILE + BTILE) + h * HALF_A + r * 8192 + w * 1024;
      __builtin_amdgcn_global_load_lds(
          (const __attribute__((address_space(1))) void*)g,
          (__attribute__((address_space(3))) void*)d, 16, 0, 0);
    }
  };
  auto stageB = [&](int buf, int t, int h) {
#pragma unroll
    for (int r = 0; r < 2; ++r) {
      int row = h * 128 + r * 64 + w * 8 + srow;
      const char* g = (const char*)(Bb + (size_t)(tileN + row) * ldb + t * BK) + scol;
      char* d = lds + buf * (ATILE + BTILE) + ATILE + h * HALF_B + r * 8192 + w * 1024;
      __builtin_amdgcn_global_load_lds(
          (const __attribute__((address_space(1))) void*)g,
          (__attribute__((address_space(3))) void*)d, 16, 0, 0);
    }
  };

  f32x4 acc[MREP][4];
#pragma unroll
  for (int m = 0; m < MREP; ++m)
#pragma unroll
    for (int nn = 0; nn < 4; ++nn) acc[m][nn] = f32x4{0.f, 0.f, 0.f, 0.f};

  // fragment ds_read (same XOR swizzle as staging)
  const int frow = l & 15;
  auto rdA = [&](int buf, int mh, int m, int kk) -> bf16x8 {
    int row = mh * (BM_ / 2) + wm * (BM_ / 4) + m * 16 + frow;
    int col = (kk * 64 + ((l >> 4) * 16)) ^ ((row & 7) << 4);
    return *reinterpret_cast<const bf16x8*>(lds + buf * (ATILE + BTILE) + row * 128 + col);
  };
  auto rdB = [&](int buf, int nh, int nn, int kk) -> bf16x8 {
    int row = nh * 128 + wn * 32 + nn * 16 + frow;
    int col = (kk * 64 + ((l >> 4) * 16)) ^ ((row & 7) << 4);
    return *reinterpret_cast<const bf16x8*>(lds + buf * (ATILE + BTILE) + ATILE + row * 128 + col);
  };

  bf16x8 avF[MQ][2];         // rotating A half set, full-K [m][kk]
  bf16x8 bv0[2][2], bv1[2][2];  // B halves, full-K [nn][kk], held per tile

  auto rdAfull = [&](int buf, int mh) {
#pragma unroll
    for (int m = 0; m < MQ; ++m)
#pragma unroll
      for (int kk = 0; kk < 2; ++kk) avF[m][kk] = rdA(buf, mh, m, kk);
  };
  auto rdBfull = [&](int buf, int nh, bf16x8 (&bv)[2][2]) {
#pragma unroll
    for (int nn = 0; nn < 2; ++nn)
#pragma unroll
      for (int kk = 0; kk < 2; ++kk) bv[nn][kk] = rdB(buf, nh, nn, kk);
  };
  auto mfc = [&](int mh, bf16x8 (&bv)[2][2], int nh) {
    __builtin_amdgcn_s_setprio(1);
#pragma unroll
    for (int m = 0; m < MQ; ++m)
#pragma unroll
      for (int nn = 0; nn < 2; ++nn)
#pragma unroll
        for (int kk = 0; kk < 2; ++kk)
          acc[mh * MQ + m][nh * 2 + nn] = __builtin_amdgcn_mfma_f32_16x16x32_bf16(
              avF[m][kk], bv[nn][kk], acc[mh * MQ + m][nh * 2 + nn], 0, 0, 0);
    __builtin_amdgcn_s_setprio(0);
  };

  // prologue: stage tile 0 (order A0,B0,B1,A1); guard A0,B0 resident
  stageA(0, 0, 0);
  stageB(0, 0, 0);
  stageB(0, 0, 1);
  stageA(0, 0, 1);
  waitvm<VPRO>();
  BARRIER();

#pragma unroll 2
  for (int t = 0; t < NT - 1; ++t) {
    const int buf = t & 1, nb = buf ^ 1;
    // P_a: (A0,B0) full-K; stage A0'+B0'; guard B1(t) for P_b
    rdAfull(buf, 0); rdBfull(buf, 0, bv0);
    stageA(nb, t + 1, 0); stageB(nb, t + 1, 0);
    waitvm<W_PA>(); BARRIER(); LGKM0();
    mfc(0, bv0, 0);
    // P_b: (A0,B1); stage B1'; guard A1(t) for P_c
    rdBfull(buf, 1, bv1);
    stageB(nb, t + 1, 1);
    waitvm<W_PB>(); BARRIER(); LGKM0();
    mfc(0, bv1, 1);
    // P_c: (A1,B1)+(A1,B0); stage A1'; guard A0',B0' for t+1 P_a
    rdAfull(buf, 1);
    stageA(nb, t + 1, 1);
    waitvm<W_PC>(); BARRIER(); LGKM0();
    mfc(1, bv1, 1); mfc(1, bv0, 0);
  }
  {  // peeled last tile: no staging; drain counted waits (same guard rule)
    const int buf = (NT - 1) & 1;
    rdAfull(buf, 0); rdBfull(buf, 0, bv0);
    waitvm<VDA>(); BARRIER(); LGKM0();
    mfc(0, bv0, 0);
    rdBfull(buf, 1, bv1);
    waitvm<0>(); BARRIER(); LGKM0();
    mfc(0, bv1, 1);
    rdAfull(buf, 1);
    LGKM0();   // own reads drained; A1 globally resident via vm<0>+barrier above
    mfc(1, bv1, 1); mfc(1, bv0, 0);
  }

  // epilogue: C/D layout (m89): col = lane&15, row = (lane>>4)*4 + j
  const int lr = (l >> 4) * 4;
  const int lc = l & 15;
#pragma unroll
  for (int mh = 0; mh < 2; ++mh) {
#pragma unroll
    for (int m = 0; m < MQ; ++m) {
#pragma unroll
      for (int nh = 0; nh < 2; ++nh) {
#pragma unroll
        for (int nn = 0; nn < 2; ++nn) {
          int gr = tileM + mh * (BM_ / 2) + wm * (BM_ / 4) + m * 16 + lr;
          int gc = tileN + nh * 128 + wn * 32 + nn * 16 + lc;
          f32x4 v = acc[mh * MQ + m][nh * 2 + nn];
          if constexpr (EP == 0 || EP == 3) {
            unsigned short* C = (unsigned short*)Cp + (size_t)z * zsC;
#pragma unroll
            for (int j = 0; j < 4; ++j) {
              float bb = (EP == 0) ? bias[gc] : bias[gr + j];
              C[(size_t)(gr + j) * ldc + gc] = f2bf(v[j] + bb);
            }
          } else {
            float* C = (float*)Cp + (size_t)z * zsC;
#pragma unroll
            for (int j = 0; j < 4; ++j)
              C[(size_t)(gr + j) * ldc + gc] = (EP == 1) ? v[j] * scale : v[j];
          }
        }
      }
    }
  }
}

// ---------------- row softmax: fp32 [8192 x 2048] -> bf16 P ----------------
__global__ __launch_bounds__(256) void softmax_kernel(const float* __restrict__ Sb,
                                                      unsigned short* __restrict__ P) {
  const size_t row = blockIdx.x;
  const float* sp = Sb + row * S_LEN;
  const int t = threadIdx.x;
  const int wid = t >> 6, lane = t & 63;
  float4 v0 = reinterpret_cast<const float4*>(sp)[t * 2];
  float4 v1 = reinterpret_cast<const float4*>(sp)[t * 2 + 1];
  float s[8] = {v0.x, v0.y, v0.z, v0.w, v1.x, v1.y, v1.z, v1.w};
  float mx = s[0];
#pragma unroll
  for (int i = 1; i < 8; ++i) mx = fmaxf(mx, s[i]);
#pragma unroll
  for (int o = 32; o > 0; o >>= 1) mx = fmaxf(mx, __shfl_xor(mx, o));
  __shared__ float redm[4];
  __shared__ float reds[4];
  if (lane == 0) redm[wid] = mx;
  __syncthreads();
  mx = fmaxf(fmaxf(redm[0], redm[1]), fmaxf(redm[2], redm[3]));
  float e[8];
  float sum = 0.f;
#pragma unroll
  for (int i = 0; i < 8; ++i) { e[i] = __expf(s[i] - mx); sum += e[i]; }
#pragma unroll
  for (int o = 32; o > 0; o >>= 1) sum += __shfl_xor(sum, o);
  if (lane == 0) reds[wid] = sum;
  __syncthreads();
  sum = reds[0] + reds[1] + reds[2] + reds[3];
  float inv = 1.0f / sum;
  ushort4 o0, o1;
  o0.x = f2bf(e[0] * inv); o0.y = f2bf(e[1] * inv); o0.z = f2bf(e[2] * inv); o0.w = f2bf(e[3] * inv);
  o1.x = f2bf(e[4] * inv); o1.y = f2bf(e[5] * inv); o1.z = f2bf(e[6] * inv); o1.w = f2bf(e[7] * inv);
  ushort4* dp = reinterpret_cast<ushort4*>(P + row * S_LEN);
  dp[t * 2] = o0;
  dp[t * 2 + 1] = o1;
}

extern "C" void kernel_launch(void* const* d_in, const int* in_sizes, int n_in,
                              void* d_out, int out_size, void* d_ws, size_t ws_size,
                              hipStream_t stream) {
  (void)in_sizes; (void)n_in; (void)out_size;
  const float* x = (const float*)d_in[0];
  const float* Wq = (const float*)d_in[1];
  const float* bq = (const float*)d_in[2];
  const float* Wk = (const float*)d_in[3];
  const float* bk = (const float*)d_in[4];
  const float* Wv = (const float*)d_in[5];
  const float* bv = (const float*)d_in[6];
  float* out = (float*)d_out;

  // workspace layout (bytes), total ~135 MB:
  //   xb   bf16 [8192][1024]    @ 0       (16 MB)
  //   Wqkb bf16 [2048][1024]    @ 16 MB   (4 MB)   -- [Wq;Wk]
  //   Wvb  bf16 [1024][1024]    @ 20 MB   (2 MB)
  //   bqk  f32  [2048]          @ 22 MB   (8 KB)
  //   QKb  bf16 [8192][2048]    @ 23 MB   (32 MB)  -- reused as P after scores
  //   Sb   f32  [4][2048][2048] @ 55 MB   (64 MB)
  //   Vt   bf16 [4][1024][2048] @ 119 MB  (16 MB)
  if (ws_size < 141557760ull) return;
  char* ws = (char*)d_ws;
  unsigned short* xb   = (unsigned short*)(ws);
  unsigned short* Wqkb = (unsigned short*)(ws + 16777216);
  unsigned short* Wvb  = (unsigned short*)(ws + 20971520);
  float*          bqk  = (float*)(ws + 23068672);
  unsigned short* QKb  = (unsigned short*)(ws + 24117248);
  float*          Sb   = (float*)(ws + 57671680);
  unsigned short* Vt   = (unsigned short*)(ws + 124780544);
  unsigned short* P    = QKb;  // alias: QKb dead after scores GEMM

  // 1) input cvt + fused weight/bias prep
  cvt_kernel<<<dim3(MROWS * DMODEL / 4 / 256), 256, 0, stream>>>(x, (ushort4*)xb, MROWS * DMODEL / 4);
  prep_kernel<<<dim3(3 * DMODEL * DMODEL / 4 / 256), 256, 0, stream>>>(
      Wq, Wk, Wv, bq, bk, (ushort4*)Wqkb, (ushort4*)Wvb, (float4*)bqk);

  // 2) QK projection: [8192x2048] = x * [Wq;Wk]^T + bqk  (grid 256 = 1 round)
  gemm8<256, 0, 16><<<dim3(8, 32, 1), 512, 0, stream>>>(
      xb, Wqkb, QKb, bqk, 1024, 1024, 2048, 1.f, 0, 0, 0);

  // 3) Vt = Wv * x^T + bv (per batch): grid (8,8,4) = 256 half-size blocks
  gemm8<128, 3, 16><<<dim3(8, 8, 4), 512, 0, stream>>>(
      Wvb, xb, Vt, bv, 1024, 1024, 2048, 1.f,
      0, (long)S_LEN * DMODEL, (long)DMODEL * S_LEN);

  // 4) scores: Sb = Q * K^T * 0.125 (per batch M=N=2048, K=1024)
  gemm8<256, 1, 16><<<dim3(8, 8, 4), 512, 0, stream>>>(
      QKb, QKb + 1024, Sb, nullptr, 2048, 2048, 2048, 0.125f,
      (long)S_LEN * 2048, (long)S_LEN * 2048, (long)S_LEN * S_LEN);

  // 5) row softmax -> bf16 P (aliases QKb)
  softmax_kernel<<<dim3(MROWS), 256, 0, stream>>>(Sb, P);

  // 6) out = P * Vt^T (per batch M=2048, N=1024, K=2048; grid 256 = 1 round)
  gemm8<128, 2, 32><<<dim3(4, 16, 4), 512, 0, stream>>>(
      P, Vt, out, nullptr, 2048, 2048, 1024, 1.f,
      (long)S_LEN * S_LEN, (long)DMODEL * S_LEN, (long)S_LEN * DMODEL);
}

// Round 14
// 165.875 us; speedup vs baseline: 1.1257x; 1.0002x over previous
//
#include <hip/hip_runtime.h>
#include <stdint.h>

#define S_LEN 2048
#define DMODEL 1024
#define NBATCH 4
#define MROWS (NBATCH * S_LEN)  // 8192

typedef __bf16 bf16x8 __attribute__((ext_vector_type(8)));
typedef float f32x4 __attribute__((ext_vector_type(4)));

__device__ __forceinline__ unsigned short f2bf(float f) {
  unsigned int x = __builtin_bit_cast(unsigned int, f);
  x += 0x7FFFu + ((x >> 16) & 1u);
  return (unsigned short)(x >> 16);
}

template <int N>
__device__ __forceinline__ void waitvm() {
  static_assert(N <= 8, "vmcnt range");
  if constexpr (N < 0) {}
  else if constexpr (N == 0) asm volatile("s_waitcnt vmcnt(0)" ::: "memory");
  else if constexpr (N == 1) asm volatile("s_waitcnt vmcnt(1)" ::: "memory");
  else if constexpr (N == 2) asm volatile("s_waitcnt vmcnt(2)" ::: "memory");
  else if constexpr (N == 3) asm volatile("s_waitcnt vmcnt(3)" ::: "memory");
  else if constexpr (N == 4) asm volatile("s_waitcnt vmcnt(4)" ::: "memory");
  else if constexpr (N == 5) asm volatile("s_waitcnt vmcnt(5)" ::: "memory");
  else if constexpr (N == 6) asm volatile("s_waitcnt vmcnt(6)" ::: "memory");
  else if constexpr (N == 7) asm volatile("s_waitcnt vmcnt(7)" ::: "memory");
  else asm volatile("s_waitcnt vmcnt(8)" ::: "memory");
}
#define BARRIER() do { __builtin_amdgcn_s_barrier(); asm volatile("" ::: "memory"); } while (0)
// m201 pattern (+rule #18): drain LDS reads once, pin MFMA below the wait.
#define LGKM0() do { asm volatile("s_waitcnt lgkmcnt(0)" ::: "memory"); \
                     __builtin_amdgcn_sched_barrier(0); } while (0)

// ---------------- convert f32 -> bf16 (vectorized) ----------------
__global__ void cvt_kernel(const float* __restrict__ src, ushort4* __restrict__ dst, int n4) {
  int i = blockIdx.x * blockDim.x + threadIdx.x;
  if (i < n4) {
    float4 v = reinterpret_cast<const float4*>(src)[i];
    ushort4 o;
    o.x = f2bf(v.x); o.y = f2bf(v.y); o.z = f2bf(v.z); o.w = f2bf(v.w);
    dst[i] = o;
  }
}

// ---------------- fused weight/bias prep: Wq,Wk->Wqkb, Wv->Wvb, bq,bk->bqk ----------------
__global__ void prep_kernel(const float* __restrict__ Wq, const float* __restrict__ Wk,
                            const float* __restrict__ Wv, const float* __restrict__ bq,
                            const float* __restrict__ bk, ushort4* __restrict__ Wqkb,
                            ushort4* __restrict__ Wvb, float4* __restrict__ bqk) {
  const int NW = DMODEL * DMODEL / 4;  // 262144 ushort4 per weight matrix
  int i = blockIdx.x * blockDim.x + threadIdx.x;
  float4 v;
  if (i < NW) v = reinterpret_cast<const float4*>(Wq)[i];
  else if (i < 2 * NW) v = reinterpret_cast<const float4*>(Wk)[i - NW];
  else v = reinterpret_cast<const float4*>(Wv)[i - 2 * NW];
  ushort4 o;
  o.x = f2bf(v.x); o.y = f2bf(v.y); o.z = f2bf(v.z); o.w = f2bf(v.w);
  if (i < 2 * NW) Wqkb[i] = o;
  else Wvb[i - 2 * NW] = o;
  if (i < 512) bqk[i] = (i < 256) ? reinterpret_cast<const float4*>(bq)[i]
                                  : reinterpret_cast<const float4*>(bk)[i - 256];
}

// ---------------- 3-phase full-K GEMM: C = A * B^T ----------------
// ROUND-14: the serializer was MFMA DEPENDENCY CHAINING, not the schedule.
// Old mf-cluster order (m,nn,kk) put kk (same-accumulator chain) innermost:
// every 2nd MFMA waited dependent-issue latency (~32cy) instead of 4.85cy
// throughput -> pipe util 2waves x 4.85/32 ~= 30% == measured MfmaUtil 31%.
// FIX: kk is now the OUTER loop of each cluster -> 8 (BM256)/4 (BM128)
// INDEPENDENT accumulators issue back-to-back (distance ~39cy >= latency).
// Per-accumulator order (kk=0 then kk=1) unchanged -> numerics identical.
// P_c merges both quadrants into one interleaved cluster (distance 2x).
// Everything else identical to r13 (3 phases, guards, swizzle, staging):
//   P_a: (A0,B0) full-K; P_b: (A0,B1); P_c: (A1,B1)+(A1,B0)
// Stage slots (t stages t+1): P_a: A0'+B0', P_b: B1', P_c: A1'.
// Guards (r7 rule: reads at p guarded by vmcnt at p-1):
//   BM256: P_a vm<6>, P_b vm<6>, P_c vm<4>; prologue vm<4>; drain vm<2>,vm<0>
//   BM128: P_a vm<4>, P_b vm<5>, P_c vm<3>; prologue vm<3>; drain vm<1>,vm<0>
// LDS swizzle: 16B-slot index ^= (row&7) via pre-swizzled GLOBAL source
// (linear LDS dest, rule #21) and identically on ds_read. 16x16x32 core.
// EP: 0 = bf16 out + bias[col]; 1 = f32 out * scale; 2 = f32 out;
//     3 = bf16 out + bias[ROW]  (Vt = Wv * x^T + bv)
template <int BM_, int EP, int NT>
__global__ __launch_bounds__(512, 2) void gemm8(
    const unsigned short* __restrict__ A, const unsigned short* __restrict__ Bm,
    void* __restrict__ Cp, const float* __restrict__ bias,
    int lda, int ldb, int ldc, float scale,
    long zsA, long zsB, long zsC) {
  constexpr int BN_ = 256;
  constexpr int BK = 64;                 // elements (128 bytes)
  constexpr int RA = BM_ / 128;          // stage loads per A-half per wave
  constexpr int HALF_A = (BM_ / 2) * 128;  // bytes
  constexpr int HALF_B = 128 * 128;
  constexpr int ATILE = BM_ * 128;
  constexpr int BTILE = BN_ * 128;
  constexpr int MREP = BM_ / 32;         // 8 or 4
  constexpr int MQ = MREP / 2;           // A frags per half (4 or 2)
  constexpr int VPRO = (BM_ == 256) ? 4 : 3;
  constexpr int W_PA = (BM_ == 256) ? 6 : 4;
  constexpr int W_PB = (BM_ == 256) ? 6 : 5;
  constexpr int W_PC = (BM_ == 256) ? 4 : 3;
  constexpr int VDA  = (BM_ == 256) ? 2 : 1;

  __shared__ alignas(16) char lds[(ATILE + BTILE) * 2];

  const int tid = threadIdx.x;
  const int l = tid & 63;
  const int w = tid >> 6;   // 0..7
  const int wm = w >> 2;    // 0..1
  const int wn = w & 3;     // 0..3

  // bijective XCD-chunked swizzle (nwg % 8 == 0 for all our grids)
  const int gx = gridDim.x;
  const int nwg = gridDim.x * gridDim.y;
  int n = blockIdx.y * gx + blockIdx.x;
  int n2 = (n & 7) * (nwg >> 3) + (n >> 3);
  const int tileM = (n2 / gx) * BM_;
  const int tileN = (n2 % gx) * BN_;

  const int z = blockIdx.z;
  const unsigned short* Ab = A + (size_t)z * zsA;
  const unsigned short* Bb = Bm + (size_t)z * zsB;

  // staging: per-lane pre-swizzled global col; linear LDS dest (wave-uniform base)
  const int srow = l >> 3;                       // 0..7 within 8-row wave chunk
  const int scol = (((l & 7) ^ srow) * 16);      // swizzled byte col within 128B row

  auto stageA = [&](int buf, int t, int h) {
#pragma unroll
    for (int r = 0; r < RA; ++r) {
      int row = h * (BM_ / 2) + r * 64 + w * 8 + srow;
      const char* g = (const char*)(Ab + (size_t)(tileM + row) * lda + t * BK) + scol;
      char* d = lds + buf * (ATILE + BTILE) + h * HALF_A + r * 8192 + w * 1024;
      __builtin_amdgcn_global_load_lds(
          (const __attribute__((address_space(1))) void*)g,
          (__attribute__((address_space(3))) void*)d, 16, 0, 0);
    }
  };
  auto stageB = [&](int buf, int t, int h) {
#pragma unroll
    for (int r = 0; r < 2; ++r) {
      int row = h * 128 + r * 64 + w * 8 + srow;
      const char* g = (const char*)(Bb + (size_t)(tileN + row) * ldb + t * BK) + scol;
      char* d = lds + buf * (ATILE + BTILE) + ATILE + h * HALF_B + r * 8192 + w * 1024;
      __builtin_amdgcn_global_load_lds(
          (const __attribute__((address_space(1))) void*)g,
          (__attribute__((address_space(3))) void*)d, 16, 0, 0);
    }
  };

  f32x4 acc[MREP][4];
#pragma unroll
  for (int m = 0; m < MREP; ++m)
#pragma unroll
    for (int nn = 0; nn < 4; ++nn) acc[m][nn] = f32x4{0.f, 0.f, 0.f, 0.f};

  // fragment ds_read (same XOR swizzle as staging)
  const int frow = l & 15;
  auto rdA = [&](int buf, int mh, int m, int kk) -> bf16x8 {
    int row = mh * (BM_ / 2) + wm * (BM_ / 4) + m * 16 + frow;
    int col = (kk * 64 + ((l >> 4) * 16)) ^ ((row & 7) << 4);
    return *reinterpret_cast<const bf16x8*>(lds + buf * (ATILE + BTILE) + row * 128 + col);
  };
  auto rdB = [&](int buf, int nh, int nn, int kk) -> bf16x8 {
    int row = nh * 128 + wn * 32 + nn * 16 + frow;
    int col = (kk * 64 + ((l >> 4) * 16)) ^ ((row & 7) << 4);
    return *reinterpret_cast<const bf16x8*>(lds + buf * (ATILE + BTILE) + ATILE + row * 128 + col);
  };

  bf16x8 avF[MQ][2];            // rotating A half set, full-K [m][kk]
  bf16x8 bv0[2][2], bv1[2][2];  // B halves, full-K [nn][kk], held per tile

  auto rdAfull = [&](int buf, int mh) {
#pragma unroll
    for (int m = 0; m < MQ; ++m)
#pragma unroll
      for (int kk = 0; kk < 2; ++kk) avF[m][kk] = rdA(buf, mh, m, kk);
  };
  auto rdBfull = [&](int buf, int nh, bf16x8 (&bv)[2][2]) {
#pragma unroll
    for (int nn = 0; nn < 2; ++nn)
#pragma unroll
      for (int kk = 0; kk < 2; ++kk) bv[nn][kk] = rdB(buf, nh, nn, kk);
  };
  // kk OUTER: per kk-step all MQ*2 accumulators are independent ->
  // MFMA issues at throughput rate, no dependent back-to-back pairs.
  auto mfc = [&](int mh, bf16x8 (&bv)[2][2], int nh) {
    __builtin_amdgcn_s_setprio(1);
#pragma unroll
    for (int kk = 0; kk < 2; ++kk)
#pragma unroll
      for (int m = 0; m < MQ; ++m)
#pragma unroll
        for (int nn = 0; nn < 2; ++nn)
          acc[mh * MQ + m][nh * 2 + nn] = __builtin_amdgcn_mfma_f32_16x16x32_bf16(
              avF[m][kk], bv[nn][kk], acc[mh * MQ + m][nh * 2 + nn], 0, 0, 0);
    __builtin_amdgcn_s_setprio(0);
  };
  // P_c merged cluster: both quadrants (nh=1 then nh=0) interleaved per kk.
  auto mfc2 = [&](int mh) {
    __builtin_amdgcn_s_setprio(1);
#pragma unroll
    for (int kk = 0; kk < 2; ++kk)
#pragma unroll
      for (int m = 0; m < MQ; ++m) {
#pragma unroll
        for (int nn = 0; nn < 2; ++nn)
          acc[mh * MQ + m][2 + nn] = __builtin_amdgcn_mfma_f32_16x16x32_bf16(
              avF[m][kk], bv1[nn][kk], acc[mh * MQ + m][2 + nn], 0, 0, 0);
#pragma unroll
        for (int nn = 0; nn < 2; ++nn)
          acc[mh * MQ + m][nn] = __builtin_amdgcn_mfma_f32_16x16x32_bf16(
              avF[m][kk], bv0[nn][kk], acc[mh * MQ + m][nn], 0, 0, 0);
      }
    __builtin_amdgcn_s_setprio(0);
  };

  // prologue: stage tile 0 (order A0,B0,B1,A1); guard A0,B0 resident
  stageA(0, 0, 0);
  stageB(0, 0, 0);
  stageB(0, 0, 1);
  stageA(0, 0, 1);
  waitvm<VPRO>();
  BARRIER();

#pragma unroll 2
  for (int t = 0; t < NT - 1; ++t) {
    const int buf = t & 1, nb = buf ^ 1;
    // P_a: (A0,B0) full-K; stage A0'+B0'; guard B1(t) for P_b
    rdAfull(buf, 0); rdBfull(buf, 0, bv0);
    stageA(nb, t + 1, 0); stageB(nb, t + 1, 0);
    waitvm<W_PA>(); BARRIER(); LGKM0();
    mfc(0, bv0, 0);
    // P_b: (A0,B1); stage B1'; guard A1(t) for P_c
    rdBfull(buf, 1, bv1);
    stageB(nb, t + 1, 1);
    waitvm<W_PB>(); BARRIER(); LGKM0();
    mfc(0, bv1, 1);
    // P_c: (A1,B1)+(A1,B0); stage A1'; guard A0',B0' for t+1 P_a
    rdAfull(buf, 1);
    stageA(nb, t + 1, 1);
    waitvm<W_PC>(); BARRIER(); LGKM0();
    mfc2(1);
  }
  {  // peeled last tile: no staging; drain counted waits (same guard rule)
    const int buf = (NT - 1) & 1;
    rdAfull(buf, 0); rdBfull(buf, 0, bv0);
    waitvm<VDA>(); BARRIER(); LGKM0();
    mfc(0, bv0, 0);
    rdBfull(buf, 1, bv1);
    waitvm<0>(); BARRIER(); LGKM0();
    mfc(0, bv1, 1);
    rdAfull(buf, 1);
    LGKM0();   // own reads drained; A1 globally resident via vm<0>+barrier above
    mfc2(1);
  }

  // epilogue: C/D layout (m89): col = lane&15, row = (lane>>4)*4 + j
  const int lr = (l >> 4) * 4;
  const int lc = l & 15;
#pragma unroll
  for (int mh = 0; mh < 2; ++mh) {
#pragma unroll
    for (int m = 0; m < MQ; ++m) {
#pragma unroll
      for (int nh = 0; nh < 2; ++nh) {
#pragma unroll
        for (int nn = 0; nn < 2; ++nn) {
          int gr = tileM + mh * (BM_ / 2) + wm * (BM_ / 4) + m * 16 + lr;
          int gc = tileN + nh * 128 + wn * 32 + nn * 16 + lc;
          f32x4 v = acc[mh * MQ + m][nh * 2 + nn];
          if constexpr (EP == 0 || EP == 3) {
            unsigned short* C = (unsigned short*)Cp + (size_t)z * zsC;
#pragma unroll
            for (int j = 0; j < 4; ++j) {
              float bb = (EP == 0) ? bias[gc] : bias[gr + j];
              C[(size_t)(gr + j) * ldc + gc] = f2bf(v[j] + bb);
            }
          } else {
            float* C = (float*)Cp + (size_t)z * zsC;
#pragma unroll
            for (int j = 0; j < 4; ++j)
              C[(size_t)(gr + j) * ldc + gc] = (EP == 1) ? v[j] * scale : v[j];
          }
        }
      }
    }
  }
}

// ---------------- row softmax: fp32 [8192 x 2048] -> bf16 P ----------------
__global__ __launch_bounds__(256) void softmax_kernel(const float* __restrict__ Sb,
                                                      unsigned short* __restrict__ P) {
  const size_t row = blockIdx.x;
  const float* sp = Sb + row * S_LEN;
  const int t = threadIdx.x;
  const int wid = t >> 6, lane = t & 63;
  float4 v0 = reinterpret_cast<const float4*>(sp)[t * 2];
  float4 v1 = reinterpret_cast<const float4*>(sp)[t * 2 + 1];
  float s[8] = {v0.x, v0.y, v0.z, v0.w, v1.x, v1.y, v1.z, v1.w};
  float mx = s[0];
#pragma unroll
  for (int i = 1; i < 8; ++i) mx = fmaxf(mx, s[i]);
#pragma unroll
  for (int o = 32; o > 0; o >>= 1) mx = fmaxf(mx, __shfl_xor(mx, o));
  __shared__ float redm[4];
  __shared__ float reds[4];
  if (lane == 0) redm[wid] = mx;
  __syncthreads();
  mx = fmaxf(fmaxf(redm[0], redm[1]), fmaxf(redm[2], redm[3]));
  float e[8];
  float sum = 0.f;
#pragma unroll
  for (int i = 0; i < 8; ++i) { e[i] = __expf(s[i] - mx); sum += e[i]; }
#pragma unroll
  for (int o = 32; o > 0; o >>= 1) sum += __shfl_xor(sum, o);
  if (lane == 0) reds[wid] = sum;
  __syncthreads();
  sum = reds[0] + reds[1] + reds[2] + reds[3];
  float inv = 1.0f / sum;
  ushort4 o0, o1;
  o0.x = f2bf(e[0] * inv); o0.y = f2bf(e[1] * inv); o0.z = f2bf(e[2] * inv); o0.w = f2bf(e[3] * inv);
  o1.x = f2bf(e[4] * inv); o1.y = f2bf(e[5] * inv); o1.z = f2bf(e[6] * inv); o1.w = f2bf(e[7] * inv);
  ushort4* dp = reinterpret_cast<ushort4*>(P + row * S_LEN);
  dp[t * 2] = o0;
  dp[t * 2 + 1] = o1;
}

extern "C" void kernel_launch(void* const* d_in, const int* in_sizes, int n_in,
                              void* d_out, int out_size, void* d_ws, size_t ws_size,
                              hipStream_t stream) {
  (void)in_sizes; (void)n_in; (void)out_size;
  const float* x = (const float*)d_in[0];
  const float* Wq = (const float*)d_in[1];
  const float* bq = (const float*)d_in[2];
  const float* Wk = (const float*)d_in[3];
  const float* bk = (const float*)d_in[4];
  const float* Wv = (const float*)d_in[5];
  const float* bv = (const float*)d_in[6];
  float* out = (float*)d_out;

  // workspace layout (bytes), total ~135 MB:
  //   xb   bf16 [8192][1024]    @ 0       (16 MB)
  //   Wqkb bf16 [2048][1024]    @ 16 MB   (4 MB)   -- [Wq;Wk]
  //   Wvb  bf16 [1024][1024]    @ 20 MB   (2 MB)
  //   bqk  f32  [2048]          @ 22 MB   (8 KB)
  //   QKb  bf16 [8192][2048]    @ 23 MB   (32 MB)  -- reused as P after scores
  //   Sb   f32  [4][2048][2048] @ 55 MB   (64 MB)
  //   Vt   bf16 [4][1024][2048] @ 119 MB  (16 MB)
  if (ws_size < 141557760ull) return;
  char* ws = (char*)d_ws;
  unsigned short* xb   = (unsigned short*)(ws);
  unsigned short* Wqkb = (unsigned short*)(ws + 16777216);
  unsigned short* Wvb  = (unsigned short*)(ws + 20971520);
  float*          bqk  = (float*)(ws + 23068672);
  unsigned short* QKb  = (unsigned short*)(ws + 24117248);
  float*          Sb   = (float*)(ws + 57671680);
  unsigned short* Vt   = (unsigned short*)(ws + 124780544);
  unsigned short* P    = QKb;  // alias: QKb dead after scores GEMM

  // 1) input cvt + fused weight/bias prep
  cvt_kernel<<<dim3(MROWS * DMODEL / 4 / 256), 256, 0, stream>>>(x, (ushort4*)xb, MROWS * DMODEL / 4);
  prep_kernel<<<dim3(3 * DMODEL * DMODEL / 4 / 256), 256, 0, stream>>>(
      Wq, Wk, Wv, bq, bk, (ushort4*)Wqkb, (ushort4*)Wvb, (float4*)bqk);

  // 2) QK projection: [8192x2048] = x * [Wq;Wk]^T + bqk  (grid 256 = 1 round)
  gemm8<256, 0, 16><<<dim3(8, 32, 1), 512, 0, stream>>>(
      xb, Wqkb, QKb, bqk, 1024, 1024, 2048, 1.f, 0, 0, 0);

  // 3) Vt = Wv * x^T + bv (per batch): grid (8,8,4) = 256 half-size blocks
  gemm8<128, 3, 16><<<dim3(8, 8, 4), 512, 0, stream>>>(
      Wvb, xb, Vt, bv, 1024, 1024, 2048, 1.f,
      0, (long)S_LEN * DMODEL, (long)DMODEL * S_LEN);

  // 4) scores: Sb = Q * K^T * 0.125 (per batch M=N=2048, K=1024)
  gemm8<256, 1, 16><<<dim3(8, 8, 4), 512, 0, stream>>>(
      QKb, QKb + 1024, Sb, nullptr, 2048, 2048, 2048, 0.125f,
      (long)S_LEN * 2048, (long)S_LEN * 2048, (long)S_LEN * S_LEN);

  // 5) row softmax -> bf16 P (aliases QKb)
  softmax_kernel<<<dim3(MROWS), 256, 0, stream>>>(Sb, P);

  // 6) out = P * Vt^T (per batch M=2048, N=1024, K=2048; grid 256 = 1 round)
  gemm8<128, 2, 32><<<dim3(4, 16, 4), 512, 0, stream>>>(
      P, Vt, out, nullptr, 2048, 2048, 1024, 1.f,
      (long)S_LEN * S_LEN, (long)DMODEL * S_LEN, (long)S_LEN * DMODEL);
}